// Round 6
// baseline (86.842 us; speedup 1.0000x reference)
//
#include <hip/hip_runtime.h>

#define EPS 1e-5f
#define TEMP 50.0f
#define CCH 64
#define HH 128
#define WW 128
#define HWSZ (HH * WW)
#define CEPS2 (CCH * EPS * EPS)
#define K2E 72.13475204444817f   // TEMP / ln(2)

// Interior tile 16 wide x 8 high (128 px), halo 20x12 = 240 px.
#define ITW 16
#define ITH 8
#define HTW 20
#define HTH 12
#define HPX (HTW * HTH)   // 240 halo pixels
#define HPAD 241          // 241 == 1 (mod 8): quarter-plane geometry spreads
                          // b128 accesses uniformly over the 8 bank-groups

typedef _Float16 h16;
typedef h16 h2v __attribute__((ext_vector_type(2)));
typedef h16 h8v __attribute__((ext_vector_type(8)));
union H8 { h8v v; h2v p[4]; };

__device__ __forceinline__ float fdot2(h2v a, h2v b, float c) {
#if __has_builtin(__builtin_amdgcn_fdot2)
    return __builtin_amdgcn_fdot2(a, b, c, false);   // v_dot2_f32_f16
#else
    return c + (float)a[0] * (float)b[0] + (float)a[1] * (float)b[1];
#endif
}

__device__ __forceinline__ h2v pkrtz(float a, float b) {
#if __has_builtin(__builtin_amdgcn_cvt_pkrtz)
    return __builtin_bit_cast(h2v, __builtin_amdgcn_cvt_pkrtz(a, b));
#else
    return (h2v){(h16)a, (h16)b};
#endif
}

__device__ __forceinline__ float fexp2(float x) {
#if __has_builtin(__builtin_amdgcn_exp2f)
    return __builtin_amdgcn_exp2f(x);                // v_exp_f32
#else
    return exp2f(x);
#endif
}

__device__ __forceinline__ float frcp(float x) {
#if __has_builtin(__builtin_amdgcn_rcpf)
    return __builtin_amdgcn_rcpf(x);                 // v_rcp_f32
#else
    return 1.f / x;
#endif
}

__device__ __forceinline__ float dpp_xor1(float x) {
#if __has_builtin(__builtin_amdgcn_mov_dpp)
    int i = __builtin_bit_cast(int, x);
    int a = __builtin_amdgcn_mov_dpp(i, 0xB1, 0xF, 0xF, true);  // quad xor 1
    return __builtin_bit_cast(float, a);
#else
    return __shfl_xor(x, 1);
#endif
}

// Quad-lane butterfly sum via DPP quad_perm (VALU pipe, no LDS traffic).
__device__ __forceinline__ float quad_sum(float x) {
#if __has_builtin(__builtin_amdgcn_mov_dpp)
    float x1 = x + dpp_xor1(x);
    int j = __builtin_bit_cast(int, x1);
    int b = __builtin_amdgcn_mov_dpp(j, 0x4E, 0xF, 0xF, true);  // quad xor 2
    return x1 + __builtin_bit_cast(float, b);
#else
    float x1 = x + __shfl_xor(x, 1);
    return x1 + __shfl_xor(x1, 2);
#endif
}

// ---- Single fused kernel. Staging v2 (vs round-1's failed direct version):
// wave w owns LDS quad w (channels 8w..8w+7). Each global load instruction
// has all 64 lanes reading CONSECUTIVE px of ONE channel plane (piecewise
// 80 B row segments) instead of round-1's 4-plane 48 B scatter. The h16
// tile bytes produced are identical to the former transpose+reload path,
// so the compute phases and output are bit-identical to round 5.
__global__ __launch_bounds__(512) void rv_onepass(const float* __restrict__ x,
                                                  float* __restrict__ out) {
    __shared__ h8v  tile[8][HPAD];   // 30856 B
    __shared__ float sh_rn[HPX];     // 960 B: per-halo-pixel 1/||x||

    const int t  = threadIdx.x;
    const int w0 = blockIdx.x * ITW;
    const int h0 = blockIdx.y * ITH;
    const int b  = blockIdx.z;

    // ---- Stage: wave w -> quad w: 4 ch-pairs x 240 px. Per lane: 32
    // independent scalar loads, 16 pkrtz, 16 b32 LDS writes. ----
    {
        const int wv = t >> 6;               // wave 0..7 == quad
        const int l  = t & 63;
        const float* xw = x + ((size_t)b * CCH + 8 * wv) * HWSZ;
        h16* dstq = (h16*)&tile[wv][0];
#pragma unroll
        for (int s = 0; s < 4; ++s) {
            const int px = s * 64 + l;       // 0..255, guard at 240
            if (px < HPX) {
                const int row = px / HTW;    // magic-mul div by 20
                const int col = px - row * HTW;
                const int gh  = h0 + row - 2;
                const int gw  = w0 + col - 2;
                const bool ok = (unsigned)gh < (unsigned)HH &&
                                (unsigned)gw < (unsigned)WW;
                const int off = gh * WW + gw;
#pragma unroll
                for (int j = 0; j < 4; ++j) {
                    float v0 = 0.f, v1 = 0.f;
                    if (ok) {
                        v0 = xw[(size_t)(2 * j) * HWSZ + off];
                        v1 = xw[(size_t)(2 * j + 1) * HWSZ + off];
                    }
                    *(h2v*)&dstq[px * 8 + 2 * j] = pkrtz(v0, v1);
                }
            }
        }
    }
    __syncthreads();

    // ---- Per-halo-pixel reciprocal norm: 2 threads/pixel (4 planes each),
    // one DPP xor1 to combine. 480/512 threads active. ----
    if (t < 2 * HPX) {
        const int px   = t >> 1;
        const int hbse = (t & 1) * 4;
        float q = 0.f;
#pragma unroll
        for (int hq = 0; hq < 4; ++hq) {
            H8 u; u.v = tile[hbse + hq][px];
#pragma unroll
            for (int j = 0; j < 4; ++j) q = fdot2(u.p[j], u.p[j], q);
        }
        const float qt = q + dpp_xor1(q);   // lanes 2px,2px+1 are adjacent
        if (!(t & 1)) sh_rn[px] = rsqrtf(qt + CEPS2);
    }
    __syncthreads();

    const int qg  = t & 3;               // channel quarter: planes 2qg, 2qg+1
    const int pix = t >> 2;              // 0..127
    const int r   = pix >> 4;            // 0..7
    const int cl  = pix & 15;            // 0..15
    const int cpx = (r + 2) * HTW + (cl + 2);

    const float rinvC2 = K2E * sh_rn[cpx];   // fold TEMP/ln2 into center norm

    H8 ctr0, ctr1;
    ctr0.v = tile[2 * qg][cpx];
    ctr1.v = tile[2 * qg + 1][cpx];

    h2v acc[8] = {};                     // unnormalized numerator, 16 ch
    float wsum = 0.f;

#pragma unroll
    for (int dr = 0; dr < 5; ++dr) {
#pragma unroll
        for (int dc = 0; dc < 5; ++dc) {
            const int npx = (r + dr) * HTW + (cl + dc);
            H8 a0, a1;
            a0.v = tile[2 * qg][npx];
            a1.v = tile[2 * qg + 1][npx];
            float d0 = 0.f, d1 = 0.f;    // two independent 4-chains
#pragma unroll
            for (int j = 0; j < 4; ++j) d0 = fdot2(ctr0.p[j], a0.p[j], d0);
#pragma unroll
            for (int j = 0; j < 4; ++j) d1 = fdot2(ctr1.p[j], a1.p[j], d1);
            float d = quad_sum(d0 + d1); // full 64-ch dot in all 4 quad lanes
            // wn = exp2(K2*sim - K2): 1 add, 2 mul/fma, 1 v_exp_f32
            const float u = (d + CEPS2) * sh_rn[npx];
            const float wn = fexp2(fmaf(u, rinvC2, -K2E));
            wsum += wn;
            const h16 wh = (h16)wn;
            const h2v w2 = {wh, wh};
#pragma unroll
            for (int j = 0; j < 4; ++j) {
                acc[j]     = a0.p[j] * w2 + acc[j];
                acc[4 + j] = a1.p[j] * w2 + acc[4 + j];
            }
        }
    }

    // ---- Normalize + store this quarter's 16 channels. Same-channel lanes
    // (every 4th) cover 16 consecutive cols -> 64 B store runs. ----
    const float rs = frcp(wsum);         // wsum in [1,25]: approx rcp fine
    const size_t obase = (size_t)b * (CCH * HWSZ)
                       + (size_t)(qg * 16) * HWSZ
                       + (h0 + r) * WW + (w0 + cl);
#pragma unroll
    for (int j = 0; j < 8; ++j) {
        const float f0 = (float)acc[j][0];
        const float f1 = (float)acc[j][1];
        out[obase + (size_t)(2 * j) * HWSZ]     = fmaf(f0, rs, EPS);
        out[obase + (size_t)(2 * j + 1) * HWSZ] = fmaf(f1, rs, EPS);
    }
}

extern "C" void kernel_launch(void* const* d_in, const int* in_sizes, int n_in,
                              void* d_out, int out_size, void* d_ws, size_t ws_size,
                              hipStream_t stream) {
    const float* x = (const float*)d_in[0];
    float* outp = (float*)d_out;
    (void)d_ws; (void)ws_size;           // workspace unused

    rv_onepass<<<dim3(WW / ITW, HH / ITH, 4), dim3(512, 1, 1), 0, stream>>>(x, outp);
}

// Round 7
// 79.060 us; speedup vs baseline: 1.0984x; 1.0984x over previous
//
#include <hip/hip_runtime.h>

#define EPS 1e-5f
#define TEMP 50.0f
#define CCH 64
#define HH 128
#define WW 128
#define HWSZ (HH * WW)
#define CEPS2 (CCH * EPS * EPS)
#define K2E 72.13475204444817f   // TEMP / ln(2)

// Interior tile 16 wide x 8 high (128 px), halo 20x12 = 240 px.
#define ITW 16
#define ITH 8
#define HTW 20
#define HTH 12
#define HPX (HTW * HTH)   // 240 halo pixels
#define HPAD 241          // 241 == 1 (mod 8): quarter-plane geometry spreads
                          // b128 accesses uniformly over the 8 bank-groups

typedef _Float16 h16;
typedef h16 h2v __attribute__((ext_vector_type(2)));
typedef h16 h8v __attribute__((ext_vector_type(8)));
union H8 { h8v v; h2v p[4]; };

__device__ __forceinline__ float fdot2(h2v a, h2v b, float c) {
#if __has_builtin(__builtin_amdgcn_fdot2)
    return __builtin_amdgcn_fdot2(a, b, c, false);   // v_dot2_f32_f16
#else
    return c + (float)a[0] * (float)b[0] + (float)a[1] * (float)b[1];
#endif
}

__device__ __forceinline__ h2v pkrtz(float a, float b) {
#if __has_builtin(__builtin_amdgcn_cvt_pkrtz)
    return __builtin_bit_cast(h2v, __builtin_amdgcn_cvt_pkrtz(a, b));
#else
    return (h2v){(h16)a, (h16)b};
#endif
}

__device__ __forceinline__ float fexp2(float x) {
#if __has_builtin(__builtin_amdgcn_exp2f)
    return __builtin_amdgcn_exp2f(x);                // v_exp_f32
#else
    return exp2f(x);
#endif
}

__device__ __forceinline__ float frcp(float x) {
#if __has_builtin(__builtin_amdgcn_rcpf)
    return __builtin_amdgcn_rcpf(x);                 // v_rcp_f32
#else
    return 1.f / x;
#endif
}

__device__ __forceinline__ float dpp_xor1(float x) {
#if __has_builtin(__builtin_amdgcn_mov_dpp)
    int i = __builtin_bit_cast(int, x);
    int a = __builtin_amdgcn_mov_dpp(i, 0xB1, 0xF, 0xF, true);  // quad xor 1
    return __builtin_bit_cast(float, a);
#else
    return __shfl_xor(x, 1);
#endif
}

// Quad-lane butterfly sum via DPP quad_perm (VALU pipe, no LDS traffic).
__device__ __forceinline__ float quad_sum(float x) {
#if __has_builtin(__builtin_amdgcn_mov_dpp)
    float x1 = x + dpp_xor1(x);
    int j = __builtin_bit_cast(int, x1);
    int b = __builtin_amdgcn_mov_dpp(j, 0x4E, 0xF, 0xF, true);  // quad xor 2
    return x1 + __builtin_bit_cast(float, b);
#else
    float x1 = x + __shfl_xor(x, 1);
    return x1 + __shfl_xor(x1, 2);
#endif
}

// ---- Kernel A: [B][C][H][W] f32 -> [B][H][W][C] f16 (channel-last) ----
// Half-row split: 1024 blocks (4/CU, 16 waves/CU). 25.2 MB total traffic
// at ~6.3 TB/s -> ~4 us: HBM-BW-bound, measured at floor.
#define TP_PAD 72       // h16 row stride: 144 B, 16B-aligned
__global__ __launch_bounds__(256) void rv_transpose(const float* __restrict__ x,
                                                    h16* __restrict__ xt) {
    __shared__ h16 buf[64][TP_PAD];          // 9216 B
    const int t = threadIdx.x;
    const int h = blockIdx.x;
    const int g = blockIdx.y;                // width half: 0 or 1
    const int b = blockIdx.z;
    const float* src = x + (size_t)b * (CCH * HWSZ) + h * WW + g * 64;
#pragma unroll 4
    for (int i = 0; i < 8; ++i) {            // 32 ch-pairs x 64 w / 256 thr
        int k = i * 256 + t;
        int w  = k & 63;                     // lane-fast: 256 B coalesced
        int cp = k >> 6;                     // channel pair 0..31
        float v0 = src[(size_t)(2 * cp) * HWSZ + w];
        float v1 = src[(size_t)(2 * cp + 1) * HWSZ + w];
        *(h2v*)&buf[w][2 * cp] = pkrtz(v0, v1);  // one b32 write
    }
    __syncthreads();
    h16* dst = xt + ((size_t)(b * HH + h) * WW + g * 64) * CCH;
#pragma unroll
    for (int j = 0; j < 2; ++j) {            // 64 px x 8 quads / 256 threads
        int idx = j * 256 + t;
        int w = idx >> 3;
        int q = idx & 7;                     // q fast: contiguous b128 stores
        h8v v = *(const h8v*)&buf[w][q * 8];
        *(h8v*)&dst[(size_t)w * CCH + q * 8] = v;
    }
}

// ---- Kernel B: fused one-pass (center logit == softmax max, exactly) ----
// Block: 512 threads = 8 waves. thread t -> pixel (t>>2), channel-quarter
// (t&3, 16 ch). sim <= 1 by Cauchy-Schwarz and center sim == 1, so each
// neighbor's weight is final on first visit (one LDS pass over the tile).
__global__ __launch_bounds__(512) void rv_fused(const h16* __restrict__ xt,
                                                float* __restrict__ out) {
    __shared__ h8v  tile[8][HPAD];   // 30856 B
    __shared__ float sh_rn[HPX];     // 960 B: per-halo-pixel 1/||x||

    const int t  = threadIdx.x;
    const int w0 = blockIdx.x * ITW;
    const int h0 = blockIdx.y * ITH;
    const int b  = blockIdx.z;

    // ---- Stage: 240 px x 8 quads = 1920 h8v. 8-lane group = one pixel's
    // 128 B contiguous global read; conflict-free b128 LDS write. ----
#pragma unroll
    for (int it = 0; it < 4; ++it) {
        int k = it * 512 + t;
        if (k < 8 * HPX) {
            int q  = k & 7;
            int px = k >> 3;             // 0..239
            int row = px / HTW;          // magic-mul div by 20
            int col = px - row * HTW;
            int gh = h0 + row - 2;
            int gw = w0 + col - 2;
            h8v v = {};
            if ((unsigned)gh < (unsigned)HH && (unsigned)gw < (unsigned)WW) {
                v = *(const h8v*)&xt[((size_t)(b * HH + gh) * WW + gw) * CCH + q * 8];
            }
            tile[q][px] = v;
        }
    }
    __syncthreads();

    // ---- Per-halo-pixel reciprocal norm: 2 threads/pixel (4 planes each),
    // one DPP xor1 to combine. 480/512 threads active. ----
    if (t < 2 * HPX) {
        const int px   = t >> 1;
        const int hbse = (t & 1) * 4;
        float q = 0.f;
#pragma unroll
        for (int hq = 0; hq < 4; ++hq) {
            H8 u; u.v = tile[hbse + hq][px];
#pragma unroll
            for (int j = 0; j < 4; ++j) q = fdot2(u.p[j], u.p[j], q);
        }
        const float qt = q + dpp_xor1(q);   // lanes 2px,2px+1 are adjacent
        if (!(t & 1)) sh_rn[px] = rsqrtf(qt + CEPS2);
    }
    __syncthreads();

    const int qg  = t & 3;               // channel quarter: planes 2qg, 2qg+1
    const int pix = t >> 2;              // 0..127
    const int r   = pix >> 4;            // 0..7
    const int cl  = pix & 15;            // 0..15
    const int cpx = (r + 2) * HTW + (cl + 2);

    const float rinvC2 = K2E * sh_rn[cpx];   // fold TEMP/ln2 into center norm

    H8 ctr0, ctr1;
    ctr0.v = tile[2 * qg][cpx];
    ctr1.v = tile[2 * qg + 1][cpx];

    h2v acc[8] = {};                     // unnormalized numerator, 16 ch
    float wsum = 0.f;

#pragma unroll
    for (int dr = 0; dr < 5; ++dr) {
#pragma unroll
        for (int dc = 0; dc < 5; ++dc) {
            const int npx = (r + dr) * HTW + (cl + dc);
            H8 a0, a1;
            a0.v = tile[2 * qg][npx];
            a1.v = tile[2 * qg + 1][npx];
            float d0 = 0.f, d1 = 0.f;    // two independent 4-chains
#pragma unroll
            for (int j = 0; j < 4; ++j) d0 = fdot2(ctr0.p[j], a0.p[j], d0);
#pragma unroll
            for (int j = 0; j < 4; ++j) d1 = fdot2(ctr1.p[j], a1.p[j], d1);
            float d = quad_sum(d0 + d1); // full 64-ch dot in all 4 quad lanes
            // wn = exp2(K2*sim - K2): 1 add, 2 mul/fma, 1 v_exp_f32
            const float u = (d + CEPS2) * sh_rn[npx];
            const float wn = fexp2(fmaf(u, rinvC2, -K2E));
            wsum += wn;
            const h16 wh = (h16)wn;
            const h2v w2 = {wh, wh};
#pragma unroll
            for (int j = 0; j < 4; ++j) {
                acc[j]     = a0.p[j] * w2 + acc[j];
                acc[4 + j] = a1.p[j] * w2 + acc[4 + j];
            }
        }
    }

    // ---- Normalize + store this quarter's 16 channels. Same-channel lanes
    // (every 4th) cover 16 consecutive cols -> 64 B store runs. ----
    const float rs = frcp(wsum);         // wsum in [1,25]: approx rcp fine
    const size_t obase = (size_t)b * (CCH * HWSZ)
                       + (size_t)(qg * 16) * HWSZ
                       + (h0 + r) * WW + (w0 + cl);
#pragma unroll
    for (int j = 0; j < 8; ++j) {
        const float f0 = (float)acc[j][0];
        const float f1 = (float)acc[j][1];
        out[obase + (size_t)(2 * j) * HWSZ]     = fmaf(f0, rs, EPS);
        out[obase + (size_t)(2 * j + 1) * HWSZ] = fmaf(f1, rs, EPS);
    }
}

extern "C" void kernel_launch(void* const* d_in, const int* in_sizes, int n_in,
                              void* d_out, int out_size, void* d_ws, size_t ws_size,
                              hipStream_t stream) {
    const float* x = (const float*)d_in[0];
    float* outp = (float*)d_out;
    h16* xt = (h16*)d_ws;    // 4*128*128*64*2 B = 8.4 MB

    rv_transpose<<<dim3(HH, 2, 4), dim3(256), 0, stream>>>(x, xt);
    rv_fused<<<dim3(WW / ITW, HH / ITH, 4), dim3(512, 1, 1), 0, stream>>>(xt, outp);
}